// Round 1
// baseline (392.731 us; speedup 1.0000x reference)
//
#include <hip/hip_runtime.h>

#define BB 2048
#define NN 200
#define DD 128
#define HH 8

typedef float f4v __attribute__((ext_vector_type(4)));

// ---------------------------------------------------------------------------
// Kernel 1: v[b][d] = sum_h Wr[h] * tanh( bq[d*8+h] + dot(q[b,:], Wq[d*8+h,:]) )
// Grid (4 j-chunks x 128 b-chunks), 256 threads. Thread owns one j = d*8+h,
// register-blocks 16 b's. Wq staged transposed in LDS (lane-consecutive reads),
// q read via wave-uniform scalar loads.  ~537 MFLOP total -> a few us.
// (unchanged from verified baseline)
// ---------------------------------------------------------------------------
__global__ __launch_bounds__(256) void proj_kernel(
    const float* __restrict__ q,    // (B, 128)
    const float* __restrict__ Wq,   // (1024, 128)
    const float* __restrict__ bq,   // (1024)
    const float* __restrict__ Wr,   // (1, 8)
    float* __restrict__ v)          // (B, 128)
{
    __shared__ float wq_s[32][257];           // [k within tile][j within chunk], padded
    const int t  = threadIdx.x;               // 0..255
    const int jc = blockIdx.x;                // 0..3   -> j chunk of 256
    const int b0 = blockIdx.y * 16;           // 0..2047 in steps of 16
    const int j  = jc * 256 + t;

    float acc[16];
#pragma unroll
    for (int i = 0; i < 16; ++i) acc[i] = 0.f;

    for (int kt = 0; kt < 4; ++kt) {          // k tiles of 32
        __syncthreads();
#pragma unroll
        for (int i = 0; i < 8; ++i) {
            int idx = t + 256 * i;            // 0..2047 f4 slots
            int jj  = idx >> 3;               // 0..255
            int kf  = idx & 7;                // 0..7
            const float4 w4 = *(const float4*)(Wq + (size_t)(jc*256 + jj)*128 + kt*32 + kf*4);
            wq_s[kf*4+0][jj] = w4.x;
            wq_s[kf*4+1][jj] = w4.y;
            wq_s[kf*4+2][jj] = w4.z;
            wq_s[kf*4+3][jj] = w4.w;
        }
        __syncthreads();

        float wreg[32];
#pragma unroll
        for (int k = 0; k < 32; ++k) wreg[k] = wq_s[k][t];   // lane-consecutive: conflict-free

#pragma unroll
        for (int bb = 0; bb < 16; ++bb) {
            const float* qrow = q + (size_t)(b0 + bb)*128 + kt*32;  // wave-uniform -> s_load
            float s = 0.f;
#pragma unroll
            for (int k = 0; k < 32; ++k) s = fmaf(qrow[k], wreg[k], s);
            acc[bb] += s;
        }
    }

    const float bqj = bq[j];
    const float wrh = Wr[j & 7];
    const int   d   = j >> 3;
#pragma unroll
    for (int bb = 0; bb < 16; ++bb) {
        float p = tanhf(acc[bb] + bqj) * wrh;
        p += __shfl_xor(p, 1);
        p += __shfl_xor(p, 2);
        p += __shfl_xor(p, 4);
        if ((t & 7) == 0) v[(size_t)(b0 + bb)*128 + d] = p;
    }
}

// ---------------------------------------------------------------------------
// Kernel 2: one block per b; online softmax over N=200 in 3 chunks {64,64,72}.
// 512 threads = 16 half-waves; half-wave owns rows {half + 16*i}.
//
// Flash-style per-half-wave combine: after the 32-lane shuffle reduce of the
// dot products, EVERY lane of a half-wave holds all of its rows' scores, so
// the local max m_h, local masked exp-sum l_h, and the weighted accumulator
// oacc = sum_i w_i * item_row_i are computed entirely lane-locally from the
// registers that already hold the item rows.  No LDS staging of item rows,
// no per-row cross-wave traffic.  Per chunk only 16 (m_h,l_h) float2's cross
// half-waves -> ONE barrier per chunk (ml_s triple-buffered by chunk), vs 3
// before.  Running (m, lsum, o4) rescaled by alpha=exp(m_old-m_new).
//
// Next chunk's global loads are issued after oacc consumes pre[] and BEFORE
// the barrier -> they stay in flight across it (HBM latency hidden under the
// combine phase), same trick as the previous version.
//
// LDS ~8.8 KB; VGPR ~60 -> 4 blocks/CU x 8 waves = 32 waves/CU.
// ---------------------------------------------------------------------------
__global__ __launch_bounds__(512, 8) void attn_kernel(
    const float* __restrict__ item,  // (B, 200, 128)
    const int*   __restrict__ mask,  // (B, 200) as int32
    const float* __restrict__ v,     // (B, 128)
    float* __restrict__ out)         // (B, 128)
{
    __shared__ float2 ml_s[3][16];                  // (m_h, l_h) per chunk per half
    __shared__ __align__(16) float stage[16][132];  // final o combine, padded

    const int t    = threadIdx.x;      // 0..511
    const int b    = blockIdx.x;
    const int seg  = t & 31;           // f4 segment within a row
    const int half = t >> 5;           // 0..15: half-wave id = row group

    const f4v vreg = *(const f4v*)(v + (size_t)b*128 + seg*4);
    const float* itemb = item + (size_t)b * (NN * 128);
    const int*   maskb = mask + (size_t)b * NN;

    float m = -3e38f, lsum = 0.f;
    f4v o4 = (f4v)0.f;

    // ---- prefetch chunk 0 rows + masks into registers ----
    f4v pre[5];
    int mk[5];
#pragma unroll
    for (int i = 0; i < 5; ++i) {
        const int row = half + 16*i;
        pre[i] = (f4v)0.f; mk[i] = 0;
        if (row < 64) {
            pre[i] = __builtin_nontemporal_load(
                (const f4v*)(itemb + (size_t)row*128 + seg*4));
            mk[i] = maskb[row];
        }
    }

    for (int c = 0; c < 3; ++c) {
        const int rows = (c == 2) ? 72 : 64;

        // ---- dot against v; 32-lane reduce => all lanes hold pp[i] ----
        float pp[5];
#pragma unroll
        for (int i = 0; i < 5; ++i) {
            const f4v f = pre[i];
            float s = f[0]*vreg[0] + f[1]*vreg[1] + f[2]*vreg[2] + f[3]*vreg[3];
#pragma unroll
            for (int off = 16; off >= 1; off >>= 1)
                s += __shfl_xor(s, off);
            pp[i] = s;
        }

        // ---- lane-local: half-wave max over its valid rows (unmasked max,
        //      matches reference) ----
        float mh = -3e38f;
#pragma unroll
        for (int i = 0; i < 5; ++i)
            if (half + 16*i < rows) mh = fmaxf(mh, pp[i]);

        // ---- lane-local: masked exp weights, sum, weighted accumulate ----
        float lh = 0.f;
        f4v oacc = (f4v)0.f;
#pragma unroll
        for (int i = 0; i < 5; ++i) {
            if (half + 16*i < rows) {
                const float w = mk[i] ? __expf(pp[i] - mh) : 0.f;
                lh += w;
                oacc[0] = fmaf(w, pre[i][0], oacc[0]);
                oacc[1] = fmaf(w, pre[i][1], oacc[1]);
                oacc[2] = fmaf(w, pre[i][2], oacc[2]);
                oacc[3] = fmaf(w, pre[i][3], oacc[3]);
            }
        }
        if (seg == 0) ml_s[c][half] = make_float2(mh, lh);

        // ---- pre[] is dead now: issue next chunk's loads BEFORE the barrier
        //      (VMEM stays in flight across s_barrier; waitcnt lands at next
        //      chunk's dot) ----
        if (c < 2) {
            const int nbase = (c + 1) * 64;
            const int nrows = (c == 1) ? 72 : 64;
#pragma unroll
            for (int i = 0; i < 5; ++i) {
                const int row = half + 16*i;
                pre[i] = (f4v)0.f; mk[i] = 0;
                if (row < nrows) {
                    pre[i] = __builtin_nontemporal_load(
                        (const f4v*)(itemb + (size_t)(nbase + row)*128 + seg*4));
                    mk[i] = maskb[nbase + row];
                }
            }
        }
        __syncthreads();   // ml_s[c] visible; triple-buffered so no top barrier

        // ---- combine across the 16 half-waves (redundant per thread;
        //      16 broadcast LDS reads, conflict-free) ----
        float mc = mh;
#pragma unroll
        for (int h = 0; h < 16; ++h)
            mc = fmaxf(mc, ml_s[c][h].x);
        const float m_new = fmaxf(m, mc);
        const float alpha = __expf(m - m_new);   // chunk 0: exp(-3e38 - x) -> 0
        float lc = 0.f;
#pragma unroll
        for (int h = 0; h < 16; ++h) {
            const float2 ml = ml_s[c][h];
            lc += ml.y * __expf(ml.x - m_new);
        }
        lsum = lsum * alpha + lc;
        const float beta = __expf(mh - m_new);   // rescale own local accumulator
        o4[0] = o4[0] * alpha + oacc[0] * beta;
        o4[1] = o4[1] * alpha + oacc[1] * beta;
        o4[2] = o4[2] * alpha + oacc[2] * beta;
        o4[3] = o4[3] * alpha + oacc[3] * beta;
        m = m_new;
    }

    // ---- combine 16 half-wave partials per d ----
    *(f4v*)(&stage[half][seg*4]) = o4;
    __syncthreads();
    if (t < 128) {
        float tot = 0.f;
#pragma unroll
        for (int h = 0; h < 16; ++h) tot += stage[h][t];
        const float denom = (lsum < 1e-7f) ? (lsum + 1.f) : lsum;
        out[(size_t)b * 128 + t] = tot / denom;
    }
}

// ---------------------------------------------------------------------------
extern "C" void kernel_launch(void* const* d_in, const int* in_sizes, int n_in,
                              void* d_out, int out_size, void* d_ws, size_t ws_size,
                              hipStream_t stream) {
    const float* item = (const float*)d_in[0];   // (2048, 200, 128)
    const float* q    = (const float*)d_in[1];   // (2048, 128)
    const int*   mask = (const int*)  d_in[2];   // (2048, 200, 1) bool -> int32
    const float* Wq   = (const float*)d_in[3];   // (1024, 128)
    const float* bq   = (const float*)d_in[4];   // (1024)
    const float* Wr   = (const float*)d_in[5];   // (1, 8)
    float* out = (float*)d_out;                  // (2048, 128)
    float* v   = (float*)d_ws;                   // scratch: 2048*128*4 = 1 MiB

    proj_kernel<<<dim3(4, 128), 256, 0, stream>>>(q, Wq, bq, Wr, v);
    attn_kernel<<<dim3(BB), 512, 0, stream>>>(item, mask, v, out);
}

// Round 2
// 320.067 us; speedup vs baseline: 1.2270x; 1.2270x over previous
//
#include <hip/hip_runtime.h>

#define BB 2048
#define NN 200
#define DD 128
#define HH 8

typedef float f4v __attribute__((ext_vector_type(4)));

// ---------------------------------------------------------------------------
// Kernel 1: v[b][d] = sum_h Wr[h] * tanh( bq[d*8+h] + dot(q[b,:], Wq[d*8+h,:]) )
// Grid (4 j-chunks x 128 b-chunks), 256 threads. Thread owns one j = d*8+h,
// register-blocks 16 b's. Wq staged transposed in LDS (lane-consecutive reads),
// q read via wave-uniform scalar loads.  ~537 MFLOP total -> a few us.
// (unchanged from verified baseline)
// ---------------------------------------------------------------------------
__global__ __launch_bounds__(256) void proj_kernel(
    const float* __restrict__ q,    // (B, 128)
    const float* __restrict__ Wq,   // (1024, 128)
    const float* __restrict__ bq,   // (1024)
    const float* __restrict__ Wr,   // (1, 8)
    float* __restrict__ v)          // (B, 128)
{
    __shared__ float wq_s[32][257];           // [k within tile][j within chunk], padded
    const int t  = threadIdx.x;               // 0..255
    const int jc = blockIdx.x;                // 0..3   -> j chunk of 256
    const int b0 = blockIdx.y * 16;           // 0..2047 in steps of 16
    const int j  = jc * 256 + t;

    float acc[16];
#pragma unroll
    for (int i = 0; i < 16; ++i) acc[i] = 0.f;

    for (int kt = 0; kt < 4; ++kt) {          // k tiles of 32
        __syncthreads();
#pragma unroll
        for (int i = 0; i < 8; ++i) {
            int idx = t + 256 * i;            // 0..2047 f4 slots
            int jj  = idx >> 3;               // 0..255
            int kf  = idx & 7;                // 0..7
            const float4 w4 = *(const float4*)(Wq + (size_t)(jc*256 + jj)*128 + kt*32 + kf*4);
            wq_s[kf*4+0][jj] = w4.x;
            wq_s[kf*4+1][jj] = w4.y;
            wq_s[kf*4+2][jj] = w4.z;
            wq_s[kf*4+3][jj] = w4.w;
        }
        __syncthreads();

        float wreg[32];
#pragma unroll
        for (int k = 0; k < 32; ++k) wreg[k] = wq_s[k][t];   // lane-consecutive: conflict-free

#pragma unroll
        for (int bb = 0; bb < 16; ++bb) {
            const float* qrow = q + (size_t)(b0 + bb)*128 + kt*32;  // wave-uniform -> s_load
            float s = 0.f;
#pragma unroll
            for (int k = 0; k < 32; ++k) s = fmaf(qrow[k], wreg[k], s);
            acc[bb] += s;
        }
    }

    const float bqj = bq[j];
    const float wrh = Wr[j & 7];
    const int   d   = j >> 3;
#pragma unroll
    for (int bb = 0; bb < 16; ++bb) {
        float p = tanhf(acc[bb] + bqj) * wrh;
        p += __shfl_xor(p, 1);
        p += __shfl_xor(p, 2);
        p += __shfl_xor(p, 4);
        if ((t & 7) == 0) v[(size_t)(b0 + bb)*128 + d] = p;
    }
}

// ---------------------------------------------------------------------------
// Kernel 2: one block per b; online softmax over N=200 in 3 chunks {64,64,72}.
// 512 threads = 16 half-waves; half-wave owns rows {half + 16*i}.
//
// ZERO in-loop synchronization: each half-wave carries a PRIVATE flash state
// (m_h, l_h, o_h[4]) across all chunks, rescaled lane-locally by
// exp(m_old - m_new).  The 16 partial states merge ONCE at the end:
//   m_g = max_h m_h;  l = sum_h l_h*exp(m_h-m_g);  o = sum_h o_h*exp(m_h-m_g)
// -- mathematically identical to the reference's global-max softmax (max is
// over UNMASKED scores; mask multiplies the exp weights, matching reference).
//
// Main loop has no barriers, no cross-wave LDS traffic: per chunk a thread
// does 5 f4 global loads (issued at end of previous chunk, in flight across
// the loop back-edge), 5x{4 FMA + 5 shfl_xor} dot-reduce, 5 broadcast LDS
// mask reads, ~6 expf, 20 FMA accumulate.  Waves free-run -> 32 waves/CU
// each with 5 KB of loads in flight (~160 KB/CU outstanding vs ~9 KB needed
// to sustain 6.3 TB/s) -> streaming-floor bound.
//
// LDS ~9.6 KB; ~45 live VGPRs (pre[5]=20 + vreg 4 + o_h 4 + state) -> fits
// the 64-VGPR cap of __launch_bounds__(512, 8): 4 blocks/CU, 32 waves/CU.
// ---------------------------------------------------------------------------
__global__ __launch_bounds__(512, 8) void attn_kernel(
    const float* __restrict__ item,  // (B, 200, 128)
    const int*   __restrict__ mask,  // (B, 200) as int32
    const float* __restrict__ v,     // (B, 128)
    float* __restrict__ out)         // (B, 128)
{
    __shared__ float  mask_s[NN];                   // 0.0 / 1.0
    __shared__ float2 ml_s[16];                     // final (m_h, l_h) per half
    __shared__ __align__(16) float stage[16][132];  // final o combine, padded

    const int t    = threadIdx.x;      // 0..511
    const int b    = blockIdx.x;
    const int seg  = t & 31;           // f4 segment within a row
    const int half = t >> 5;           // 0..15: half-wave id = row group

    const f4v vreg = *(const f4v*)(v + (size_t)b*128 + seg*4);
    const float* itemb = item + (size_t)b * (NN * 128);

    // stage mask as float once (coalesced; broadcast reads later)
    if (t < NN) mask_s[t] = mask[(size_t)b * NN + t] ? 1.f : 0.f;

    // ---- prefetch chunk 0 rows into registers ----
    f4v pre[5];
#pragma unroll
    for (int i = 0; i < 5; ++i) {
        const int row = half + 16*i;
        pre[i] = (f4v)0.f;
        if (row < 64)
            pre[i] = __builtin_nontemporal_load(
                (const f4v*)(itemb + (size_t)row*128 + seg*4));
    }
    __syncthreads();   // mask_s visible (the ONLY pre-epilogue barrier)

    float mh = -3e38f, lh = 0.f;
    f4v oh = (f4v)0.f;

    for (int c = 0; c < 3; ++c) {
        const int base = c * 64;
        const int rows = (c == 2) ? 72 : 64;

        // ---- dot against v; 32-lane butterfly => all lanes hold pp[i] ----
        float pp[5];
#pragma unroll
        for (int i = 0; i < 5; ++i) {
            const f4v f = pre[i];
            float s = f[0]*vreg[0] + f[1]*vreg[1] + f[2]*vreg[2] + f[3]*vreg[3];
#pragma unroll
            for (int off = 16; off >= 1; off >>= 1)
                s += __shfl_xor(s, off);
            pp[i] = s;
        }

        // ---- private running max over this half's valid rows (unmasked) ----
        float mn = mh;
#pragma unroll
        for (int i = 0; i < 5; ++i)
            if (half + 16*i < rows) mn = fmaxf(mn, pp[i]);

        const float alpha = __expf(mh - mn);   // chunk 0: exp(-3e38-x) -> 0
        mh = mn;
        lh *= alpha;
        oh[0] *= alpha; oh[1] *= alpha; oh[2] *= alpha; oh[3] *= alpha;

        // ---- masked exp weights + lane-local weighted accumulate ----
#pragma unroll
        for (int i = 0; i < 5; ++i) {
            const int row = half + 16*i;
            if (row < rows) {
                const float w = mask_s[base + row] * __expf(pp[i] - mn);
                lh += w;
                oh[0] = fmaf(w, pre[i][0], oh[0]);
                oh[1] = fmaf(w, pre[i][1], oh[1]);
                oh[2] = fmaf(w, pre[i][2], oh[2]);
                oh[3] = fmaf(w, pre[i][3], oh[3]);
            }
        }

        // ---- pre[] dead: issue next chunk's loads (in flight across the
        //      back-edge; no barrier anywhere in this loop) ----
        if (c < 2) {
            const int nbase = (c + 1) * 64;
            const int nrows = (c == 1) ? 72 : 64;
#pragma unroll
            for (int i = 0; i < 5; ++i) {
                const int row = half + 16*i;
                pre[i] = (f4v)0.f;
                if (row < nrows)
                    pre[i] = __builtin_nontemporal_load(
                        (const f4v*)(itemb + (size_t)(nbase + row)*128 + seg*4));
            }
        }
    }

    // ---- merge the 16 private flash states, once ----
    if (seg == 0) ml_s[half] = make_float2(mh, lh);
    *(f4v*)(&stage[half][seg*4]) = oh;     // lane-consecutive f4: conflict-free
    __syncthreads();

    if (t < 128) {
        float mg = -3e38f;
#pragma unroll
        for (int h = 0; h < 16; ++h) mg = fmaxf(mg, ml_s[h].x);
        float lsum = 0.f, tot = 0.f;
#pragma unroll
        for (int h = 0; h < 16; ++h) {
            const float sc = __expf(ml_s[h].x - mg);
            lsum += ml_s[h].y * sc;
            tot  = fmaf(stage[h][t], sc, tot);   // consecutive lanes: conflict-free
        }
        const float denom = (lsum < 1e-7f) ? (lsum + 1.f) : lsum;
        out[(size_t)b * 128 + t] = tot / denom;
    }
}

// ---------------------------------------------------------------------------
extern "C" void kernel_launch(void* const* d_in, const int* in_sizes, int n_in,
                              void* d_out, int out_size, void* d_ws, size_t ws_size,
                              hipStream_t stream) {
    const float* item = (const float*)d_in[0];   // (2048, 200, 128)
    const float* q    = (const float*)d_in[1];   // (2048, 128)
    const int*   mask = (const int*)  d_in[2];   // (2048, 200, 1) bool -> int32
    const float* Wq   = (const float*)d_in[3];   // (1024, 128)
    const float* bq   = (const float*)d_in[4];   // (1024)
    const float* Wr   = (const float*)d_in[5];   // (1, 8)
    float* out = (float*)d_out;                  // (2048, 128)
    float* v   = (float*)d_ws;                   // scratch: 2048*128*4 = 1 MiB

    proj_kernel<<<dim3(4, 128), 256, 0, stream>>>(q, Wq, bq, Wr, v);
    attn_kernel<<<dim3(BB), 512, 0, stream>>>(item, mask, v, out);
}